// Round 6
// baseline (568.737 us; speedup 1.0000x reference)
//
#include <hip/hip_runtime.h>
#include <hip/hip_bf16.h>
#include <stdint.h>

// Problem dims (fixed by the reference)
#define E_   8
#define S_   2048
#define B_   4
#define D_   1024
#define F_   4096
#define NTOK (S_ * B_)   // 8192 tokens
#define MAXT 72          // max (expert, m-tile) entries: 8192/128 + 8

typedef __attribute__((ext_vector_type(8))) __bf16 bf16x8;
typedef __attribute__((ext_vector_type(4))) float  f32x4;

// ---- workspace layout (bytes) ----
#define WS_LIST 4096                       // 8192 ints (token list, grouped by expert)
#define WS_XB   65536                      // NTOK*D bf16   = 16,777,216 B
#define WS_W1T  (WS_XB + 16777216)         // E*F*D bf16    = 67,108,864 B  -> [E][F][D]
#define WS_W2T  WS_W1T                     // E*D*F bf16 (reuses W1T region) -> [E][D][F]
#define WS_H    (WS_W1T + 67108864)        // NTOK*F bf16   = 67,108,864 B

__device__ __forceinline__ void gload_lds16(const void* g, void* l) {
    __builtin_amdgcn_global_load_lds(
        (const __attribute__((address_space(1))) void*)g,
        (__attribute__((address_space(3))) void*)l, 16, 0, 0);
}

// ---------------- pass 1: expert grouping ----------------
__global__ void build_lists(const int* __restrict__ mask,
                            int* __restrict__ meta, int* __restrict__ list) {
    __shared__ int cnt[E_], cur[E_];
    int tid = threadIdx.x;
    if (tid < E_) cnt[tid] = 0;
    __syncthreads();
    for (int t = tid; t < NTOK; t += 256) atomicAdd(&cnt[mask[t]], 1);
    __syncthreads();
    if (tid == 0) {
        int acc = 0, nt = 0;
        for (int e = 0; e < E_; ++e) {
            meta[e] = cnt[e];
            meta[8 + e] = acc;
            cur[e] = acc;
            acc += cnt[e];
        }
        for (int e = 0; e < E_; ++e) {
            int mt = (cnt[e] + 127) >> 7;
            for (int m = 0; m < mt; ++m) meta[32 + nt++] = (e << 16) | m;
        }
        meta[16] = nt;
        for (; nt < MAXT; ++nt) meta[32 + nt] = -1;
    }
    __syncthreads();
    for (int t = tid; t < NTOK; t += 256) {
        int e = mask[t];
        int pos = atomicAdd(&cur[e], 1);
        list[pos] = t;
    }
}

// ---------------- pass 2a: x fp32 -> bf16 ----------------
__global__ void convert_x_kernel(const float* __restrict__ x,
                                 __hip_bfloat16* __restrict__ xb) {
    size_t i = ((size_t)blockIdx.x * blockDim.x + threadIdx.x) * 4;
    const float4 v = *(const float4*)(x + i);
    union { __hip_bfloat16 h[4]; uint2 u; } o;
    o.h[0] = __float2bfloat16(v.x);
    o.h[1] = __float2bfloat16(v.y);
    o.h[2] = __float2bfloat16(v.z);
    o.h[3] = __float2bfloat16(v.w);
    *(uint2*)(xb + i) = o.u;
}

// ---------------- pass 2b: W [E][R][C] fp32 -> [E][C][R] bf16 ----------------
// Pure-register 8x8 block transpose: no LDS, no bank conflicts. Reads paired
// float4 (16-lane 256B runs); writes bf16x8 (4-lane 64B runs). All register
// indices compile-time after unroll.
__global__ void transpose_convert(const float* __restrict__ src,
                                  __hip_bfloat16* __restrict__ dst,
                                  int R, int C) {
    size_t off = (size_t)blockIdx.z * R * C;
    const float* s = src + off;
    __hip_bfloat16* d = dst + off;
    int r0 = blockIdx.y * 128, c0 = blockIdx.x * 128;
    int t = threadIdx.x;
    int rb = t >> 4, cb = t & 15;   // 16 x 16 threads of 8x8 blocks
    const float* sp = s + (size_t)(r0 + 8 * rb) * C + c0 + 8 * cb;
    float v[8][8];
#pragma unroll
    for (int j = 0; j < 8; ++j) {
        *(float4*)&v[j][0] = *(const float4*)(sp + (size_t)j * C);
        *(float4*)&v[j][4] = *(const float4*)(sp + (size_t)j * C + 4);
    }
    __hip_bfloat16* dp = d + (size_t)(c0 + 8 * cb) * R + r0 + 8 * rb;
#pragma unroll
    for (int i = 0; i < 8; ++i) {
        union { __hip_bfloat16 h[8]; uint4 u; } o;
#pragma unroll
        for (int j = 0; j < 8; ++j) o.h[j] = __float2bfloat16(v[j][i]);
        *(uint4*)(dp + (size_t)i * R) = o.u;
    }
}

// ---------------- grouped GEMM, 128x128x32 tile, 4 waves, dbuf 32KB ----------------
// LAYER==1: A = xb rows gathered via list, out = relu(.+b1) -> H (bf16, grouped rows)
// LAYER==2: A = H rows (already grouped),   out = .+b2 -> scatter fp32 via list
// LDS rows (64B = 4 chunks of 16B) are chunk-XOR-swizzled: LDS[row][c] holds
// global chunk c ^ ((row>>1)&3); fragment reads XOR the same mask back.
// Spreads the b128 fragment reads from 8-way to 2-way (free) bank aliasing.
template <int KDIM, int NDIM, int LAYER>
__global__ __launch_bounds__(256, 4) void gemm_kernel(
    const uint8_t* __restrict__ Abase,  // bf16 rows of length KDIM
    const uint8_t* __restrict__ Wt,     // bf16 [E][NDIM][KDIM] (K-contiguous)
    const float* __restrict__ bias,     // [E][NDIM]
    const int* __restrict__ meta, const int* __restrict__ list,
    __hip_bfloat16* __restrict__ Hout, float* __restrict__ Oout) {
    constexpr int NT = NDIM / 128;
    // T1: bijective XCD swizzle (m204), n fastest within an XCD chunk.
    const int nblk = MAXT * NT;
    int orig = blockIdx.x;
    int q = nblk >> 3, r = nblk & 7;
    int xcd = orig & 7, idx = orig >> 3;
    int swz = (xcd < r ? xcd * (q + 1) : r * (q + 1) + (xcd - r) * q) + idx;
    int te = meta[32 + swz / NT];
    if (te < 0) return;
    const int e = te >> 16, mt = te & 0xffff;
    const int cnt = meta[e], bse = meta[8 + e];
    const int n0 = (swz % NT) * 128;
    const int tid = threadIdx.x, wv = tid >> 6, l = tid & 63;
    const int wr = wv >> 1, wc = wv & 1;

    __shared__ __align__(16) uint8_t smem[2][16384];  // per buf: As 8KB | Bs 8KB

    const uint8_t* WtE = Wt + (size_t)e * NDIM * KDIM * 2;

    // Staging: lane covers row p*64+wv*16+(l>>2), LDS chunk l&3. Source chunk
    // pre-XOR-ed by (row>>1)&3 = (l>>3)&3 so LDS[row][c] = G[row][c^s(row)].
    size_t agoff[2], bgoff[2];
#pragma unroll
    for (int p = 0; p < 2; ++p) {
        int rrow = p * 64 + wv * 16 + (l >> 2);
        int grow = mt * 128 + rrow;
        int pidx = bse + (grow < cnt ? grow : cnt - 1);
        size_t arow = (LAYER == 1) ? (size_t)list[pidx] : (size_t)pidx;
        size_t chunk = (size_t)(((l & 3) ^ ((l >> 3) & 3)) * 16);
        agoff[p] = arow * (KDIM * 2) + chunk;
        bgoff[p] = (size_t)(n0 + rrow) * (KDIM * 2) + chunk;
    }

    f32x4 acc[4][4] = {};

    auto stage = [&](int buf, int kt) {
        uint8_t* As = &smem[buf][0];
        uint8_t* Bs = &smem[buf][8192];
        size_t kb = (size_t)kt * 64;  // 32 bf16 per K-step
#pragma unroll
        for (int p = 0; p < 2; ++p) {
            gload_lds16(Abase + agoff[p] + kb, As + (p * 64 + wv * 16) * 64);
            gload_lds16(WtE + bgoff[p] + kb, Bs + (p * 64 + wv * 16) * 64);
        }
    };

    auto compute = [&](int buf) {
        const uint8_t* As = &smem[buf][0];
        const uint8_t* Bs = &smem[buf][8192];
        bf16x8 a[4], b[4];
#pragma unroll
        for (int mi = 0; mi < 4; ++mi) {
            int row = wr * 64 + mi * 16 + (l & 15);
            a[mi] = *(const bf16x8*)(As + row * 64 +
                                     (((l >> 4) ^ ((row >> 1) & 3)) << 4));
        }
#pragma unroll
        for (int ni = 0; ni < 4; ++ni) {
            int row = wc * 64 + ni * 16 + (l & 15);
            b[ni] = *(const bf16x8*)(Bs + row * 64 +
                                     (((l >> 4) ^ ((row >> 1) & 3)) << 4));
        }
#pragma unroll
        for (int mi = 0; mi < 4; ++mi)
#pragma unroll
            for (int ni = 0; ni < 4; ++ni)
                acc[mi][ni] = __builtin_amdgcn_mfma_f32_16x16x32_bf16(
                    a[mi], b[ni], acc[mi][ni], 0, 0, 0);
    };

    const int KT = KDIM / 32;
    stage(0, 0);
    __syncthreads();  // drains vmcnt(0)
    int cur = 0;
    for (int kt = 0; kt < KT - 1; ++kt) {
        stage(cur ^ 1, kt + 1);  // prefetch next K-tile; hidden under compute
        compute(cur);
        __syncthreads();
        cur ^= 1;
    }
    compute(cur);

    // epilogue: C/D layout col = l&15, row = (l>>4)*4 + i  [m89-verified]
#pragma unroll
    for (int mi = 0; mi < 4; ++mi) {
#pragma unroll
        for (int i = 0; i < 4; ++i) {
            int rl = wr * 64 + mi * 16 + (l >> 4) * 4 + i;
            int grow = mt * 128 + rl;
            if (grow < cnt) {
#pragma unroll
                for (int ni = 0; ni < 4; ++ni) {
                    int col = n0 + wc * 64 + ni * 16 + (l & 15);
                    float v = acc[mi][ni][i] + bias[(size_t)e * NDIM + col];
                    if (LAYER == 1) {
                        v = fmaxf(v, 0.f);
                        Hout[(size_t)(bse + grow) * NDIM + col] = __float2bfloat16(v);
                    } else {
                        int tok = list[bse + grow];
                        Oout[(size_t)tok * NDIM + col] = v;
                    }
                }
            }
        }
    }
}

extern "C" void kernel_launch(void* const* d_in, const int* in_sizes, int n_in,
                              void* d_out, int out_size, void* d_ws, size_t ws_size,
                              hipStream_t stream) {
    const float* x  = (const float*)d_in[0];
    const float* W1 = (const float*)d_in[1];
    const float* b1 = (const float*)d_in[2];
    const float* W2 = (const float*)d_in[3];
    const float* b2 = (const float*)d_in[4];
    const int* mask = (const int*)d_in[5];
    float* out = (float*)d_out;

    uint8_t* ws = (uint8_t*)d_ws;
    int* meta = (int*)ws;
    int* list = (int*)(ws + WS_LIST);
    __hip_bfloat16* xb  = (__hip_bfloat16*)(ws + WS_XB);
    __hip_bfloat16* w1t = (__hip_bfloat16*)(ws + WS_W1T);
    __hip_bfloat16* w2t = (__hip_bfloat16*)(ws + WS_W2T);
    __hip_bfloat16* H   = (__hip_bfloat16*)(ws + WS_H);

    build_lists<<<1, 256, 0, stream>>>(mask, meta, list);
    convert_x_kernel<<<NTOK * D_ / 4 / 256, 256, 0, stream>>>(x, xb);
    // W1 [E][D][F] -> [E][F][D]
    transpose_convert<<<dim3(F_ / 128, D_ / 128, E_), 256, 0, stream>>>(W1, w1t, D_, F_);
    // layer 1: M=tokens, N=F, K=D
    gemm_kernel<D_, F_, 1><<<MAXT * (F_ / 128), 256, 0, stream>>>(
        (const uint8_t*)xb, (const uint8_t*)w1t, b1, meta, list, H, nullptr);
    // W2 [E][F][D] -> [E][D][F]  (reuses W1t region; W1t dead after GEMM1)
    transpose_convert<<<dim3(D_ / 128, F_ / 128, E_), 256, 0, stream>>>(W2, w2t, F_, D_);
    // layer 2: M=tokens, N=D, K=F
    gemm_kernel<F_, D_, 2><<<MAXT * (D_ / 128), 256, 0, stream>>>(
        (const uint8_t*)H, (const uint8_t*)w2t, b2, meta, list, nullptr, out);
}